// Round 1
// baseline (617.976 us; speedup 1.0000x reference)
//
#include <hip/hip_runtime.h>

namespace {

constexpr int SEQ   = 2048;
constexpr int BATCH = 2;
constexpr int NH    = 16;
constexpr int DH    = 64;
constexpr int BQ    = 64;   // q rows per block
constexpr int BK    = 64;   // keys per tile
constexpr int PITCH = 68;   // 64 + 4 floats pad (keeps float4 alignment, breaks pow2 bank stride)
constexpr float SCALE = 0.125f;            // 1/sqrt(64)
constexpr int ROWSTRIDE = BATCH * NH * DH; // 2048 floats between consecutive tokens

// Layout: inputs (s, b, h, d) fp32; output (s, b, h*d) fp32.
// One block per (q-tile, b*h). 256 threads = 16x16 (tx, ty).
// Thread (ty, tx) owns q rows qr = ty*4+i and:
//   - score keys kc = tx + 16*j   (cyclic -> 2-way LDS bank aliasing, free)
//   - output cols oc = tx*4..tx*4+3 (contiguous float4)
__global__ __launch_bounds__(256, 1) void fa_fwd(
    const float* __restrict__ Qg, const float* __restrict__ Kg,
    const float* __restrict__ Vg, float* __restrict__ Og) {
  const int qt  = blockIdx.x;
  const int bh  = blockIdx.y;
  const int bi  = bh >> 4;          // bh / NH
  const int hi  = bh & (NH - 1);
  const int tid = threadIdx.x;
  const int tx  = tid & 15;
  const int ty  = tid >> 4;

  __shared__ float Qs[BQ * PITCH];
  __shared__ float Ks[BK * PITCH];  // reused to hold P after the barrier
  __shared__ float Vs[BK * PITCH];

  const size_t base = (size_t)(bi * NH + hi) * DH;

  // ---- load Q tile (pre-scaled by 1/8); each 16-lane group loads one full 256B row ----
  {
    const int q0 = qt * BQ;
#pragma unroll
    for (int k = 0; k < 4; ++k) {
      const int idx = tid + 256 * k;      // 0..1023
      const int r   = idx >> 4;           // row 0..63
      const int c4  = (idx & 15) * 4;     // float col
      float4 v = *(const float4*)(Qg + base + (size_t)(q0 + r) * ROWSTRIDE + c4);
      v.x *= SCALE; v.y *= SCALE; v.z *= SCALE; v.w *= SCALE;
      *(float4*)(Qs + r * PITCH + c4) = v;
    }
  }

  float4 oacc[4];
  float  mrow[4], lrow[4];
#pragma unroll
  for (int i = 0; i < 4; ++i) {
    oacc[i] = make_float4(0.f, 0.f, 0.f, 0.f);
    mrow[i] = -1e30f;
    lrow[i] = 0.f;
  }

  for (int kt = 0; kt <= qt; ++kt) {
    __syncthreads();  // previous iteration's P/V reads done before overwrite
    // ---- stage K and V tiles ----
    {
      const int k0 = kt * BK;
#pragma unroll
      for (int k = 0; k < 4; ++k) {
        const int idx = tid + 256 * k;
        const int r   = idx >> 4;
        const int c4  = (idx & 15) * 4;
        *(float4*)(Ks + r * PITCH + c4) =
            *(const float4*)(Kg + base + (size_t)(k0 + r) * ROWSTRIDE + c4);
        *(float4*)(Vs + r * PITCH + c4) =
            *(const float4*)(Vg + base + (size_t)(k0 + r) * ROWSTRIDE + c4);
      }
    }
    __syncthreads();

    // ---- scores: s[i][j] = (Q/8)[qr_i] . K[kc_j] ----
    float s[4][4];
#pragma unroll
    for (int i = 0; i < 4; ++i)
#pragma unroll
      for (int j = 0; j < 4; ++j) s[i][j] = 0.f;

#pragma unroll 4
    for (int dk = 0; dk < 16; ++dk) {
      float4 qv[4], kv[4];
#pragma unroll
      for (int i = 0; i < 4; ++i)
        qv[i] = *(const float4*)(Qs + (ty * 4 + i) * PITCH + dk * 4);
#pragma unroll
      for (int j = 0; j < 4; ++j)
        kv[j] = *(const float4*)(Ks + (tx + 16 * j) * PITCH + dk * 4);
#pragma unroll
      for (int i = 0; i < 4; ++i)
#pragma unroll
        for (int j = 0; j < 4; ++j) {
          s[i][j] += qv[i].x * kv[j].x;
          s[i][j] += qv[i].y * kv[j].y;
          s[i][j] += qv[i].z * kv[j].z;
          s[i][j] += qv[i].w * kv[j].w;
        }
    }

    // ---- causal mask (diagonal tile only; kt<qt tiles are fully unmasked) ----
    if (kt == qt) {
#pragma unroll
      for (int i = 0; i < 4; ++i) {
        const int qr = ty * 4 + i;
#pragma unroll
        for (int j = 0; j < 4; ++j) {
          const int kc = tx + 16 * j;
          if (kc > qr) s[i][j] = -1e30f;  // exp underflows to exactly 0, same as ref's -10000
        }
      }
    }

    // ---- online softmax (row state per q row; reduce across the 16 tx lanes) ----
#pragma unroll
    for (int i = 0; i < 4; ++i) {
      float mx = fmaxf(fmaxf(s[i][0], s[i][1]), fmaxf(s[i][2], s[i][3]));
#pragma unroll
      for (int off = 8; off >= 1; off >>= 1) mx = fmaxf(mx, __shfl_xor(mx, off));
      const float mnew  = fmaxf(mrow[i], mx);
      const float alpha = __expf(mrow[i] - mnew);
      float sum = 0.f;
#pragma unroll
      for (int j = 0; j < 4; ++j) {
        const float p = __expf(s[i][j] - mnew);
        s[i][j] = p;
        sum += p;
      }
#pragma unroll
      for (int off = 8; off >= 1; off >>= 1) sum += __shfl_xor(sum, off);
      lrow[i] = lrow[i] * alpha + sum;
      mrow[i] = mnew;
      oacc[i].x *= alpha; oacc[i].y *= alpha; oacc[i].z *= alpha; oacc[i].w *= alpha;
    }

    __syncthreads();  // all waves done reading Ks before it becomes P
    // ---- write P into the (now free) K buffer ----
#pragma unroll
    for (int i = 0; i < 4; ++i)
#pragma unroll
      for (int j = 0; j < 4; ++j)
        Ks[(ty * 4 + i) * PITCH + tx + 16 * j] = s[i][j];
    __syncthreads();

    // ---- O += P . V ----
#pragma unroll 4
    for (int kk4 = 0; kk4 < 16; ++kk4) {
      float4 pv[4], vv[4];
#pragma unroll
      for (int i = 0; i < 4; ++i)
        pv[i] = *(const float4*)(Ks + (ty * 4 + i) * PITCH + kk4 * 4);
#pragma unroll
      for (int c = 0; c < 4; ++c)
        vv[c] = *(const float4*)(Vs + (kk4 * 4 + c) * PITCH + tx * 4);
#pragma unroll
      for (int i = 0; i < 4; ++i) {
        oacc[i].x += pv[i].x * vv[0].x + pv[i].y * vv[1].x + pv[i].z * vv[2].x + pv[i].w * vv[3].x;
        oacc[i].y += pv[i].x * vv[0].y + pv[i].y * vv[1].y + pv[i].z * vv[2].y + pv[i].w * vv[3].y;
        oacc[i].z += pv[i].x * vv[0].z + pv[i].y * vv[1].z + pv[i].z * vv[2].z + pv[i].w * vv[3].z;
        oacc[i].w += pv[i].x * vv[0].w + pv[i].y * vv[1].w + pv[i].z * vv[2].w + pv[i].w * vv[3].w;
      }
    }
  }

  // ---- epilogue: normalize and store (s, b, h*d) ----
#pragma unroll
  for (int i = 0; i < 4; ++i) {
    const float rl = 1.f / lrow[i];
    const int   row = qt * BQ + ty * 4 + i;
    float4 o = oacc[i];
    o.x *= rl; o.y *= rl; o.z *= rl; o.w *= rl;
    *(float4*)(Og + ((size_t)(row * BATCH + bi) * NH + hi) * DH + tx * 4) = o;
  }
}

}  // namespace

extern "C" void kernel_launch(void* const* d_in, const int* in_sizes, int n_in,
                              void* d_out, int out_size, void* d_ws, size_t ws_size,
                              hipStream_t stream) {
  const float* Q = (const float*)d_in[0];
  const float* K = (const float*)d_in[1];
  const float* V = (const float*)d_in[2];
  float* O = (float*)d_out;
  dim3 grid(SEQ / BQ, BATCH * NH);  // 32 q-tiles x 32 (b*h)
  fa_fwd<<<grid, dim3(256), 0, stream>>>(Q, K, V, O);
}

// Round 2
// 207.674 us; speedup vs baseline: 2.9757x; 2.9757x over previous
//
#include <hip/hip_runtime.h>

namespace {

constexpr int S   = 2048;
constexpr int NBH = 32;   // b*h
constexpr int D   = 64;
constexpr int BQ  = 128;  // q rows per block (4 waves x 32)
constexpr int BK  = 64;   // keys per tile
constexpr int LP  = 72;   // LDS pitch in bf16 elems: b128-aligned, ~2-way banks (free)

typedef short  bf16x8 __attribute__((ext_vector_type(8)));
typedef float  f32x4  __attribute__((ext_vector_type(4)));
typedef unsigned short u16;

__device__ inline u16 f2bf(float f) {
  union { float f; unsigned u; } v; v.f = f;
  unsigned u = v.u + 0x7fffu + ((v.u >> 16) & 1u);  // RNE
  return (u16)(u >> 16);
}

// ---- pre-pass: (s,b,h,d) fp32 -> (b,h,s,d) bf16, optional scale ----
__global__ void conv_qk(const float* __restrict__ in, u16* __restrict__ out, float scale) {
  const int idx4  = blockIdx.x * 256 + threadIdx.x;  // one float4 per thread
  const int c4    = (idx4 & 15) * 4;
  const int rowid = idx4 >> 4;            // t*32 + bh  (bh = bi*16+hi)
  const int t = rowid >> 5, bh = rowid & 31;
  const float4 v = *(const float4*)(in + (size_t)idx4 * 4);
  u16 o[4] = { f2bf(v.x * scale), f2bf(v.y * scale), f2bf(v.z * scale), f2bf(v.w * scale) };
  *(ushort4*)(out + ((size_t)bh * S + t) * D + c4) = *(const ushort4*)o;
}

// ---- pre-pass: V (s,b,h,d) fp32 -> Vt (b,h,d,s) bf16, via LDS tile transpose ----
__global__ void conv_v(const float* __restrict__ in, u16* __restrict__ out) {
  __shared__ u16 T[D * LP];
  const int tid = threadIdx.x;
  const int t0  = blockIdx.x * 64;
  const int bh  = blockIdx.y;
#pragma unroll
  for (int k = 0; k < 4; ++k) {
    const int idx = tid + 256 * k;        // 64 tokens x 16 float4
    const int r   = idx >> 4;             // token within tile
    const int c4  = (idx & 15) * 4;       // d
    const float4 v = *(const float4*)(in + ((size_t)(t0 + r) * NBH + bh) * D + c4);
    T[(c4 + 0) * LP + r] = f2bf(v.x);
    T[(c4 + 1) * LP + r] = f2bf(v.y);
    T[(c4 + 2) * LP + r] = f2bf(v.z);
    T[(c4 + 3) * LP + r] = f2bf(v.w);
  }
  __syncthreads();
#pragma unroll
  for (int k = 0; k < 2; ++k) {
    const int idx = tid + 256 * k;        // 64 d-rows x 8 chunks(16B)
    const int d   = idx >> 3;
    const int c8  = (idx & 7) * 8;
    *(uint4*)(out + ((size_t)(bh * D + d)) * S + t0 + c8) = *(const uint4*)(T + d * LP + c8);
  }
}

// ---- main: MFMA flash attention ----
// Fragment layouts (gfx950 mfma_f32_16x16x32_bf16, measured m89/m91/m120):
//   A: lane holds A[m=lane&15][k=quad*8+j], j=0..7  (one ds_read_b128)
//   B: lane holds B[k=quad*8+j][n=lane&15]
//   C/D: lane holds C[row=quad*4+reg][col=lane&15], reg=0..3
__global__ __launch_bounds__(256) void fa_mfma(
    const u16* __restrict__ Qb, const u16* __restrict__ Kb,
    const u16* __restrict__ Vt, float* __restrict__ Og) {
  const int qt = blockIdx.x, bh = blockIdx.y;
  const int bi = bh >> 4, hi = bh & 15;
  const int tid  = threadIdx.x;
  const int lane = tid & 63, wave = tid >> 6;
  const int col  = lane & 15, quad = lane >> 4;

  __shared__ u16 Ks[BK * LP];
  __shared__ u16 Vs[D * LP];       // Vs[d][key]
  __shared__ u16 Ps[4][32 * LP];   // per-wave P tile (32 q rows x 64 keys)

  // Q A-fragments (wave owns 32 q rows = 2 groups of 16), read direct from global
  bf16x8 qf[2][2];
  {
    const u16* q = Qb + ((size_t)bh * S + qt * BQ + wave * 32) * D;
#pragma unroll
    for (int g = 0; g < 2; ++g)
#pragma unroll
      for (int c = 0; c < 2; ++c)
        qf[g][c] = *(const bf16x8*)(q + (g * 16 + col) * D + c * 32 + quad * 8);
  }

  f32x4 Oacc[2][4];
  float m_[2][4], l_[2][4];
#pragma unroll
  for (int g = 0; g < 2; ++g)
#pragma unroll
    for (int r = 0; r < 4; ++r) {
      Oacc[g][r] = (f32x4){0.f, 0.f, 0.f, 0.f};
      m_[g][r] = -1e30f; l_[g][r] = 0.f;
    }

  const int ktn = 2 * qt + 2;  // causal: keys up to (qt+1)*128-1
  for (int kt = 0; kt < ktn; ++kt) {
    __syncthreads();  // all waves done with previous Ks/Vs
    // stage K and V tiles (bf16, coalesced 16B chunks)
#pragma unroll
    for (int k = 0; k < 2; ++k) {
      const int idx = tid + 256 * k;   // 64 rows x 8 chunks
      const int r   = idx >> 3;
      const int c8  = (idx & 7) * 8;
      *(uint4*)(&Ks[r * LP + c8]) =
          *(const uint4*)(Kb + ((size_t)bh * S + kt * BK + r) * D + c8);
      *(uint4*)(&Vs[r * LP + c8]) =
          *(const uint4*)(Vt + ((size_t)(bh * D + r)) * S + kt * BK + c8);
    }
    __syncthreads();

    // ---- S = (Q/8) K^T : 16 MFMAs, 8 B-frag reads (each feeds both q-groups) ----
    f32x4 Sacc[2][4];
#pragma unroll
    for (int n = 0; n < 4; ++n) {
      const bf16x8 bk0 = *(const bf16x8*)(&Ks[(n * 16 + col) * LP + quad * 8]);
      const bf16x8 bk1 = *(const bf16x8*)(&Ks[(n * 16 + col) * LP + 32 + quad * 8]);
#pragma unroll
      for (int g = 0; g < 2; ++g) {
        f32x4 z = (f32x4){0.f, 0.f, 0.f, 0.f};
        z = __builtin_amdgcn_mfma_f32_16x16x32_bf16(qf[g][0], bk0, z, 0, 0, 0);
        Sacc[g][n] = __builtin_amdgcn_mfma_f32_16x16x32_bf16(qf[g][1], bk1, z, 0, 0, 0);
      }
    }

    // ---- causal mask (only the last two tiles touch the diagonal) ----
    if (kt >= 2 * qt) {
#pragma unroll
      for (int g = 0; g < 2; ++g)
#pragma unroll
        for (int n = 0; n < 4; ++n)
#pragma unroll
          for (int r = 0; r < 4; ++r) {
            const int key  = kt * BK + n * 16 + col;
            const int qrow = qt * BQ + wave * 32 + g * 16 + quad * 4 + r;
            if (key > qrow) Sacc[g][n][r] = -1e30f;
          }
    }

    // ---- online softmax (rows live across 16 lanes of each quad group) ----
#pragma unroll
    for (int g = 0; g < 2; ++g) {
      float mx[4];
#pragma unroll
      for (int r = 0; r < 4; ++r)
        mx[r] = fmaxf(fmaxf(Sacc[g][0][r], Sacc[g][1][r]),
                      fmaxf(Sacc[g][2][r], Sacc[g][3][r]));
#pragma unroll
      for (int off = 1; off <= 8; off <<= 1)
#pragma unroll
        for (int r = 0; r < 4; ++r) mx[r] = fmaxf(mx[r], __shfl_xor(mx[r], off));

      float al[4], rs[4];
#pragma unroll
      for (int r = 0; r < 4; ++r) {
        const float mn = fmaxf(m_[g][r], mx[r]);
        al[r] = __expf(m_[g][r] - mn);
        m_[g][r] = mn;
        rs[r] = 0.f;
      }
#pragma unroll
      for (int n = 0; n < 4; ++n)
#pragma unroll
        for (int r = 0; r < 4; ++r) {
          const float p = __expf(Sacc[g][n][r] - m_[g][r]);
          Sacc[g][n][r] = p;
          rs[r] += p;
        }
#pragma unroll
      for (int off = 1; off <= 8; off <<= 1)
#pragma unroll
        for (int r = 0; r < 4; ++r) rs[r] += __shfl_xor(rs[r], off);
#pragma unroll
      for (int r = 0; r < 4; ++r) l_[g][r] = l_[g][r] * al[r] + rs[r];
#pragma unroll
      for (int n = 0; n < 4; ++n)
#pragma unroll
        for (int r = 0; r < 4; ++r) Oacc[g][n][r] *= al[r];

      // P (C-layout) -> per-wave LDS tile in row-major for A-frag readback
#pragma unroll
      for (int n = 0; n < 4; ++n)
#pragma unroll
        for (int r = 0; r < 4; ++r)
          Ps[wave][(g * 16 + quad * 4 + r) * LP + n * 16 + col] = f2bf(Sacc[g][n][r]);
    }

    // ---- O += P V : 16 MFMAs, 8 V B-frag reads + 4 P A-frag reads ----
    bf16x8 pf[2][2];
#pragma unroll
    for (int g = 0; g < 2; ++g)
#pragma unroll
      for (int c = 0; c < 2; ++c)
        pf[g][c] = *(const bf16x8*)(&Ps[wave][(g * 16 + col) * LP + c * 32 + quad * 8]);
#pragma unroll
    for (int n = 0; n < 4; ++n) {
      const bf16x8 bv0 = *(const bf16x8*)(&Vs[(n * 16 + col) * LP + quad * 8]);
      const bf16x8 bv1 = *(const bf16x8*)(&Vs[(n * 16 + col) * LP + 32 + quad * 8]);
#pragma unroll
      for (int g = 0; g < 2; ++g) {
        Oacc[g][n] = __builtin_amdgcn_mfma_f32_16x16x32_bf16(pf[g][0], bv0, Oacc[g][n], 0, 0, 0);
        Oacc[g][n] = __builtin_amdgcn_mfma_f32_16x16x32_bf16(pf[g][1], bv1, Oacc[g][n], 0, 0, 0);
      }
    }
  }

  // ---- epilogue: normalize, store (s, b, h*d) fp32 ----
#pragma unroll
  for (int g = 0; g < 2; ++g)
#pragma unroll
    for (int r = 0; r < 4; ++r) {
      const float rl  = 1.f / l_[g][r];
      const int   row = qt * BQ + wave * 32 + g * 16 + quad * 4 + r;
      float* o = Og + ((size_t)(row * 2 + bi) * 16 + hi) * D;
#pragma unroll
      for (int n = 0; n < 4; ++n) o[n * 16 + col] = Oacc[g][n][r] * rl;
    }
}

}  // namespace

extern "C" void kernel_launch(void* const* d_in, const int* in_sizes, int n_in,
                              void* d_out, int out_size, void* d_ws, size_t ws_size,
                              hipStream_t stream) {
  const float* Q = (const float*)d_in[0];
  const float* K = (const float*)d_in[1];
  const float* V = (const float*)d_in[2];
  float* O = (float*)d_out;

  u16* Qb = (u16*)d_ws;                    // 8 MB each
  u16* Kb = Qb + (size_t)NBH * S * D;
  u16* Vb = Kb + (size_t)NBH * S * D;

  conv_qk<<<4096, 256, 0, stream>>>(Q, Qb, 0.125f);
  conv_qk<<<4096, 256, 0, stream>>>(K, Kb, 1.0f);
  conv_v<<<dim3(32, 32), 256, 0, stream>>>(V, Vb);
  fa_mfma<<<dim3(S / BQ, NBH), 256, 0, stream>>>(Qb, Kb, Vb, O);
}